// Round 2
// baseline (390.038 us; speedup 1.0000x reference)
//
#include <hip/hip_runtime.h>

typedef __attribute__((ext_vector_type(8))) __bf16 bf16x8;
typedef __attribute__((ext_vector_type(4))) float  f32x4;

#define DEV __device__ __forceinline__

DEV void async_copy16(const void* g, void* l) {
  __builtin_amdgcn_global_load_lds((const __attribute__((address_space(1))) void*)g,
                                   (__attribute__((address_space(3))) void*)l, 16, 0, 0);
}

// load element i of a raw input as float; isbf chooses bf16 vs fp32 interpretation
DEV float ldf(const void* p, size_t i, int isbf) {
  if (isbf) {
    unsigned int w = ((unsigned int)((const unsigned short*)p)[i]) << 16;
    float f; __builtin_memcpy(&f, &w, 4); return f;
  }
  return ((const float*)p)[i];
}

// ---- dtype probe: flag=1 if inputs are bf16, 0 if fp32 ----
__global__ void detect_dtype(const unsigned short* __restrict__ x, int* __restrict__ flag) {
  int bad = 0;
#pragma unroll
  for (int i = 0; i < 4; i++) {
    unsigned short u = x[threadIdx.x + i * 64];
    int e = (u >> 7) & 0xFF;
    if (e >= 0x90) bad = 1;  // |v| >= 2^17 or Inf/NaN -> cannot be real bf16 data
  }
  int anybad = __any(bad);
  if (threadIdx.x == 0) flag[0] = anybad ? 0 : 1;
}

// ---- cast raw input (fp32 or bf16 per flag) to bf16 ----
__global__ __launch_bounds__(256) void cast_to_bf16(const void* __restrict__ in,
                                                    __bf16* __restrict__ out,
                                                    const int* __restrict__ flag, int n) {
  int isbf = flag[0];
  int i = blockIdx.x * 256 + threadIdx.x;
  if (i < n) out[i] = (__bf16)ldf(in, i, isbf);
}

// ---- transpose raw weight [R][C] (fp32/bf16 per flag) -> bf16 [C][R] ----
__global__ __launch_bounds__(256) void transpose_cast(const void* __restrict__ in,
                                                      __bf16* __restrict__ out,
                                                      const int* __restrict__ flag,
                                                      int R, int C) {
  __shared__ float tile[32][33];
  int isbf = flag[0];
  const int tx = threadIdx.x & 31, ty = threadIdx.x >> 5;
  const int r0 = blockIdx.y * 32, c0 = blockIdx.x * 32;
#pragma unroll
  for (int i = 0; i < 4; i++) {
    int r = ty + i * 8;
    tile[r][tx] = ldf(in, (size_t)(r0 + r) * C + c0 + tx, isbf);
  }
  __syncthreads();
#pragma unroll
  for (int i = 0; i < 4; i++) {
    int r = ty + i * 8;
    out[(size_t)(c0 + r) * R + r0 + tx] = (__bf16)tile[tx][r];
  }
}

// ---- internal bf16 transpose (for V): in[z][R][C] -> out[z][C][R] ----
__global__ __launch_bounds__(256) void transpose_v(const __bf16* __restrict__ in,
                                                   __bf16* __restrict__ out, int R, int C) {
  __shared__ __bf16 tile[32][33];
  const size_t bofs = (size_t)blockIdx.z * R * C;
  in += bofs; out += bofs;
  const int tx = threadIdx.x & 31, ty = threadIdx.x >> 5;
  const int r0 = blockIdx.y * 32, c0 = blockIdx.x * 32;
#pragma unroll
  for (int i = 0; i < 4; i++) {
    int r = ty + i * 8;
    tile[r][tx] = in[(size_t)(r0 + r) * C + c0 + tx];
  }
  __syncthreads();
#pragma unroll
  for (int i = 0; i < 4; i++) {
    int r = ty + i * 8;
    out[(size_t)(c0 + r) * R + r0 + tx] = tile[tx][r];
  }
}

// ---- bias buffer: float[4096] = [bq|bk|bv|bo] ----
__global__ void build_bias(const void* bq, const void* bk, const void* bv, const void* bo,
                           float* __restrict__ bias, const int* __restrict__ flag) {
  int isbf = flag[0];
  int i = blockIdx.x * 256 + threadIdx.x;
  if (i < 1024)      bias[i] = ldf(bq, i, isbf);
  else if (i < 2048) bias[i] = ldf(bk, i - 1024, isbf);
  else if (i < 3072) bias[i] = ldf(bv, i - 2048, isbf);
  else if (i < 4096) bias[i] = ldf(bo, i - 3072, isbf);
}

// ---------------- GEMM: C[M,N] = A[M,K] @ Bt[N,K]^T + bias ----------------
// 128x128 tile, BK=64, 256 threads (2x2 waves of 64x64), 16x16x32 bf16 MFMA.
// LDS: per 64-elem row, 8 chunks of 8; chunk c stored at slot c ^ (row&7)
// (XOR swizzle keeps global_load_lds staging lane-contiguous AND frag reads conflict-free)
// DYN=0: output bf16 always. DYN=1: output dtype chosen by flag (bf16/fp32).
template <int DYN>
__global__ __launch_bounds__(256, 2) void gemm_bt(const __bf16* __restrict__ A,
                                                  const __bf16* __restrict__ Bt,
                                                  const float* __restrict__ bias,
                                                  void* __restrict__ Cout,
                                                  const int* __restrict__ flag,
                                                  int M, int N, int K) {
  __shared__ __align__(16) __bf16 As[128 * 64];
  __shared__ __align__(16) __bf16 Bs[128 * 64];
  const int tid = threadIdx.x;
  const int wid = tid >> 6, lane = tid & 63;
  const int m_blk = blockIdx.x * 128, n_blk = blockIdx.y * 128;
  const int wm = (wid & 1) * 64, wn = (wid >> 1) * 64;
  const int l8 = lane >> 3, l7 = lane & 7;
  const int cc = l7 ^ (l8 & 7);           // chunk this lane fetches when staging
  const int q4 = lane >> 4, l15 = lane & 15;

  f32x4 acc[4][4] = {};

  for (int kb = 0; kb < K; kb += 64) {
    __syncthreads();
#pragma unroll
    for (int i = 0; i < 4; i++) {
      int row = i * 32 + wid * 8 + l8;    // local row 0..127
      async_copy16(A + (size_t)(m_blk + row) * K + kb + cc * 8,
                   As + (i * 32 + wid * 8) * 64);
      async_copy16(Bt + (size_t)(n_blk + row) * K + kb + cc * 8,
                   Bs + (i * 32 + wid * 8) * 64);
    }
    __syncthreads();
#pragma unroll
    for (int k0 = 0; k0 < 64; k0 += 32) {
      bf16x8 a[4], b[4];
#pragma unroll
      for (int i = 0; i < 4; i++) {
        int ra = wm + i * 16 + l15;
        int ba = ra * 8 + (((k0 >> 3) + q4) ^ (ra & 7));
        a[i] = *(const bf16x8*)&As[ba * 8];
        int rb = wn + i * 16 + l15;
        int bb = rb * 8 + (((k0 >> 3) + q4) ^ (rb & 7));
        b[i] = *(const bf16x8*)&Bs[bb * 8];
      }
#pragma unroll
      for (int i = 0; i < 4; i++)
#pragma unroll
        for (int j = 0; j < 4; j++)
          acc[i][j] = __builtin_amdgcn_mfma_f32_16x16x32_bf16(a[i], b[j], acc[i][j], 0, 0, 0);
    }
  }

  const int isbf = DYN ? flag[0] : 1;
  float bcol[4];
#pragma unroll
  for (int j = 0; j < 4; j++) bcol[j] = bias[n_blk + wn + j * 16 + l15];
#pragma unroll
  for (int i = 0; i < 4; i++)
#pragma unroll
    for (int j = 0; j < 4; j++) {
      int col = n_blk + wn + j * 16 + l15;
#pragma unroll
      for (int r = 0; r < 4; r++) {
        int row = m_blk + wm + i * 16 + q4 * 4 + r;
        float v = acc[i][j][r] + bcol[j];
        size_t idx = (size_t)row * N + col;
        if (isbf) ((__bf16*)Cout)[idx] = (__bf16)v;
        else      ((float*)Cout)[idx] = v;
      }
    }
}

// ---------------- per-head LN + RoPE + cast; head channels via h*192 scramble ----------------
// Qp gets folded scale: 1/sqrt(64) * log2(e) so attention uses exp2.
__global__ __launch_bounds__(256) void ln_rope(const __bf16* __restrict__ qkv,
                                               const void* __restrict__ rcos,
                                               const void* __restrict__ rsin,
                                               const void* __restrict__ qw,
                                               const void* __restrict__ qb,
                                               const void* __restrict__ kw,
                                               const void* __restrict__ kb_,
                                               const int* __restrict__ flag,
                                               __bf16* __restrict__ Qp,
                                               __bf16* __restrict__ Kp,
                                               __bf16* __restrict__ Vbf) {
  const int isbf = flag[0];
  const int unit = blockIdx.x * 4 + (threadIdx.x >> 6);
  const int lane = threadIdx.x & 63;
  const int h = unit & 15, n = (unit >> 4) & 2047, b = unit >> 15;
  const size_t tok = (size_t)b * 2048 + n;
  const __bf16* base = qkv + tok * 3072 + h * 192;
  float qv = (float)base[lane], kv = (float)base[64 + lane], vv = (float)base[128 + lane];

  // LN over 64 lanes
  float sq = qv, sk = kv;
#pragma unroll
  for (int m = 1; m < 64; m <<= 1) { sq += __shfl_xor(sq, m, 64); sk += __shfl_xor(sk, m, 64); }
  float muq = sq * (1.0f / 64.0f), muk = sk * (1.0f / 64.0f);
  float tq = qv - muq, tk = kv - muk;
  float vq = tq * tq, vk = tk * tk;
#pragma unroll
  for (int m = 1; m < 64; m <<= 1) { vq += __shfl_xor(vq, m, 64); vk += __shfl_xor(vk, m, 64); }
  float rsq = rsqrtf(vq * (1.0f / 64.0f) + 1e-6f);
  float rsk = rsqrtf(vk * (1.0f / 64.0f) + 1e-6f);
  float qn = tq * rsq * ldf(qw, lane, isbf) + ldf(qb, lane, isbf);
  float kn = tk * rsk * ldf(kw, lane, isbf) + ldf(kb_, lane, isbf);

  // RoPE
  float c = ldf(rcos, tok * 64 + lane, isbf), s = ldf(rsin, tok * 64 + lane, isbf);
  float qpart = __shfl_xor(qn, 32, 64), kpart = __shfl_xor(kn, 32, 64);
  float qrh = (lane < 32) ? -qpart : qpart;
  float krh = (lane < 32) ? -kpart : kpart;
  float qr = qn * c + qrh * s;
  float kr = kn * c + krh * s;

  const size_t oidx = ((size_t)(b * 16 + h) * 2048 + n) * 64 + lane;
  Qp[oidx] = (__bf16)(qr * 0.1803368801111204f);  // 0.125 * log2(e)
  Kp[oidx] = (__bf16)kr;
  Vbf[oidx] = (__bf16)vv;
}

// ---------------- flash attention ----------------
// grid (16 q-blocks, 32 bh), 256 threads. Each wave: 32 q rows, loop 32-key steps.
// K/V^T tiles staged in MFMA-fragment register order -> linear conflict-free ds_read_b128.
__global__ __launch_bounds__(256, 2) void attn(const __bf16* __restrict__ Qp,
                                               const __bf16* __restrict__ Kp,
                                               const __bf16* __restrict__ Vt,
                                               __bf16* __restrict__ Obuf) {
  __shared__ __align__(16) __bf16 sK[2048];       // 4 frag-groups x 64 lanes x 8
  __shared__ __align__(16) __bf16 sV[2048];
  __shared__ __align__(16) __bf16 sP[4 * 1280];   // per-wave 32 x 40 (pad 8)
  const int tid = threadIdx.x, wid = tid >> 6, lane = tid & 63;
  const int q4 = lane >> 4, l15 = lane & 15;
  const int bh = blockIdx.y;
  const int q0 = blockIdx.x * 128 + wid * 32;
  const __bf16* Qb = Qp + (size_t)bh * 2048 * 64;
  const __bf16* Kb = Kp + (size_t)bh * 2048 * 64;
  const __bf16* Vb = Vt + (size_t)bh * 64 * 2048;

  bf16x8 aq[2][2];
#pragma unroll
  for (int sub = 0; sub < 2; sub++)
#pragma unroll
    for (int c2 = 0; c2 < 2; c2++)
      aq[sub][c2] = *(const bf16x8*)&Qb[(size_t)(q0 + sub * 16 + l15) * 64 + c2 * 32 + q4 * 8];

  f32x4 o[2][4] = {};
  float mst[2][4], lst[2][4];
#pragma unroll
  for (int s = 0; s < 2; s++)
#pragma unroll
    for (int r = 0; r < 4; r++) { mst[s][r] = -3.0e38f; lst[s][r] = 0.0f; }

  const int s_ = wid & 1, c2_ = wid >> 1;  // this wave's K staging group

  for (int kt = 0; kt < 2048; kt += 32) {
    __syncthreads();
    async_copy16(Kb + (size_t)(kt + s_ * 16 + l15) * 64 + c2_ * 32 + q4 * 8, sK + wid * 512);
    async_copy16(Vb + (size_t)(wid * 16 + l15) * 2048 + kt + q4 * 8, sV + wid * 512);
    __syncthreads();

    // QK^T: S[32q x 32k] per wave
    bf16x8 bk[2][2];
#pragma unroll
    for (int s = 0; s < 2; s++)
#pragma unroll
      for (int c2 = 0; c2 < 2; c2++)
        bk[s][c2] = *(const bf16x8*)&sK[((c2 * 2 + s) * 64 + lane) * 8];
    f32x4 sc[2][2];
#pragma unroll
    for (int sub = 0; sub < 2; sub++)
#pragma unroll
      for (int s = 0; s < 2; s++) {
        f32x4 z = {0.f, 0.f, 0.f, 0.f};
        z = __builtin_amdgcn_mfma_f32_16x16x32_bf16(aq[sub][0], bk[s][0], z, 0, 0, 0);
        z = __builtin_amdgcn_mfma_f32_16x16x32_bf16(aq[sub][1], bk[s][1], z, 0, 0, 0);
        sc[sub][s] = z;
      }

    // online softmax (base-2; scale folded into Q)
#pragma unroll
    for (int sub = 0; sub < 2; sub++) {
      float rmax[4], rsum[4], al[4];
#pragma unroll
      for (int r = 0; r < 4; r++) rmax[r] = fmaxf(sc[sub][0][r], sc[sub][1][r]);
#pragma unroll
      for (int mk = 1; mk < 16; mk <<= 1)
#pragma unroll
        for (int r = 0; r < 4; r++) rmax[r] = fmaxf(rmax[r], __shfl_xor(rmax[r], mk, 64));
#pragma unroll
      for (int r = 0; r < 4; r++) {
        float mn = fmaxf(mst[sub][r], rmax[r]);
        al[r] = exp2f(mst[sub][r] - mn);
        mst[sub][r] = mn;
        float p0 = exp2f(sc[sub][0][r] - mn);
        float p1 = exp2f(sc[sub][1][r] - mn);
        int rowp = wid * 1280 + (sub * 16 + q4 * 4 + r) * 40;
        sP[rowp + l15] = (__bf16)p0;
        sP[rowp + 16 + l15] = (__bf16)p1;
        rsum[r] = p0 + p1;
      }
#pragma unroll
      for (int mk = 1; mk < 16; mk <<= 1)
#pragma unroll
        for (int r = 0; r < 4; r++) rsum[r] += __shfl_xor(rsum[r], mk, 64);
#pragma unroll
      for (int r = 0; r < 4; r++) lst[sub][r] = lst[sub][r] * al[r] + rsum[r];
#pragma unroll
      for (int dt = 0; dt < 4; dt++)
#pragma unroll
        for (int r = 0; r < 4; r++) o[sub][dt][r] *= al[r];
    }
    asm volatile("s_waitcnt lgkmcnt(0)" ::: "memory");

    // PV: A = P (LDS round-trip), B = V^T frags
    bf16x8 pa[2], vb[4];
#pragma unroll
    for (int sub = 0; sub < 2; sub++)
      pa[sub] = *(const bf16x8*)&sP[wid * 1280 + (sub * 16 + l15) * 40 + q4 * 8];
#pragma unroll
    for (int dt = 0; dt < 4; dt++)
      vb[dt] = *(const bf16x8*)&sV[(dt * 64 + lane) * 8];
#pragma unroll
    for (int sub = 0; sub < 2; sub++)
#pragma unroll
      for (int dt = 0; dt < 4; dt++)
        o[sub][dt] = __builtin_amdgcn_mfma_f32_16x16x32_bf16(pa[sub], vb[dt], o[sub][dt], 0, 0, 0);
  }

  const int b = bh >> 4, h = bh & 15;
#pragma unroll
  for (int sub = 0; sub < 2; sub++) {
    float rl[4];
#pragma unroll
    for (int r = 0; r < 4; r++) rl[r] = 1.0f / lst[sub][r];
#pragma unroll
    for (int dt = 0; dt < 4; dt++)
#pragma unroll
      for (int r = 0; r < 4; r++) {
        int q = q0 + sub * 16 + q4 * 4 + r;
        int d = dt * 16 + l15;
        Obuf[((size_t)(b * 2048 + q)) * 1024 + h * 64 + d] = (__bf16)(o[sub][dt][r] * rl[r]);
      }
  }
}

extern "C" void kernel_launch(void* const* d_in, const int* in_sizes, int n_in,
                              void* d_out, int out_size, void* d_ws, size_t ws_size,
                              hipStream_t stream) {
  const void* x   = d_in[0];
  const void* rc  = d_in[1];
  const void* rs  = d_in[2];
  const void* Wq  = d_in[3];
  const void* bq  = d_in[4];
  const void* Wk  = d_in[5];
  const void* bk  = d_in[6];
  const void* Wv  = d_in[7];
  const void* bv  = d_in[8];
  const void* qnw = d_in[9];
  const void* qnb = d_in[10];
  const void* knw = d_in[11];
  const void* knb = d_in[12];
  const void* Wo  = d_in[13];
  const void* bo  = d_in[14];

  char* ws = (char*)d_ws;
  // [0, 25165824): qkv bf16 [4096][3072]; after it dies:
  //   Vt  at 0        : bf16 [32][64][2048] (8 MB)
  //   Obuf at 16777216: bf16 [4096][1024]   (8 MB, ends exactly at 25165824)
  __bf16* qkv  = (__bf16*)ws;
  __bf16* Vt   = (__bf16*)ws;
  __bf16* Obuf = (__bf16*)(ws + 16777216);
  __bf16* Qp   = (__bf16*)(ws + 25165824);   // [32][2048][64]
  __bf16* Kp   = (__bf16*)(ws + 33554432);
  __bf16* Vbf  = (__bf16*)(ws + 41943040);
  __bf16* Wt   = (__bf16*)(ws + 50331648);   // [3072][1024] = (Wq^T;Wk^T;Wv^T)
  __bf16* Wot  = (__bf16*)(ws + 56623104);   // [1024][1024]
  float*  bias = (float*)(ws + 58720256);    // [4096] = bq|bk|bv|bo
  __bf16* x_bf = (__bf16*)(ws + 58736640);   // [4096][1024]
  int*    flag = (int*)(ws + 67125248);

  detect_dtype<<<1, 64, 0, stream>>>((const unsigned short*)x, flag);
  cast_to_bf16<<<16384, 256, 0, stream>>>(x, x_bf, flag, 4096 * 1024);
  transpose_cast<<<dim3(32, 32), 256, 0, stream>>>(Wq, Wt, flag, 1024, 1024);
  transpose_cast<<<dim3(32, 32), 256, 0, stream>>>(Wk, Wt + 1024 * 1024, flag, 1024, 1024);
  transpose_cast<<<dim3(32, 32), 256, 0, stream>>>(Wv, Wt + 2 * 1024 * 1024, flag, 1024, 1024);
  transpose_cast<<<dim3(32, 32), 256, 0, stream>>>(Wo, Wot, flag, 1024, 1024);
  build_bias<<<16, 256, 0, stream>>>(bq, bk, bv, bo, bias, flag);

  gemm_bt<0><<<dim3(32, 24), 256, 0, stream>>>(x_bf, Wt, bias, qkv, flag, 4096, 3072, 1024);
  ln_rope<<<16384, 256, 0, stream>>>(qkv, rc, rs, qnw, qnb, knw, knb, flag, Qp, Kp, Vbf);
  transpose_v<<<dim3(2, 64, 32), 256, 0, stream>>>(Vbf, Vt, 2048, 64);
  attn<<<dim3(16, 32), 256, 0, stream>>>(Qp, Kp, Vt, Obuf);
  gemm_bt<1><<<dim3(32, 8), 256, 0, stream>>>(Obuf, Wot, bias + 3072, d_out, flag, 4096, 1024, 1024);
}

// Round 4
// 272.254 us; speedup vs baseline: 1.4326x; 1.4326x over previous
//
#include <hip/hip_runtime.h>

typedef __attribute__((ext_vector_type(8))) __bf16 bf16x8;
typedef __attribute__((ext_vector_type(4))) float  f32x4;

#define DEV __device__ __forceinline__

DEV void async_copy16(const void* g, void* l) {
  __builtin_amdgcn_global_load_lds((const __attribute__((address_space(1))) void*)g,
                                   (__attribute__((address_space(3))) void*)l, 16, 0, 0);
}

// load element i of a raw input as float; isbf chooses bf16 vs fp32 interpretation
DEV float ldf(const void* p, size_t i, int isbf) {
  if (isbf) {
    unsigned int w = ((unsigned int)((const unsigned short*)p)[i]) << 16;
    float f; __builtin_memcpy(&f, &w, 4); return f;
  }
  return ((const float*)p)[i];
}

// ---- dtype probe: flag=1 if inputs are bf16, 0 if fp32 ----
__global__ void detect_dtype(const unsigned short* __restrict__ x, int* __restrict__ flag) {
  int bad = 0;
#pragma unroll
  for (int i = 0; i < 4; i++) {
    unsigned short u = x[threadIdx.x + i * 64];
    int e = (u >> 7) & 0xFF;
    if (e >= 0x90) bad = 1;  // |v| >= 2^17 or Inf/NaN -> cannot be real bf16 data
  }
  int anybad = __any(bad);
  if (threadIdx.x == 0) flag[0] = anybad ? 0 : 1;
}

// ---- cast raw input (fp32 or bf16 per flag) to bf16 ----
__global__ __launch_bounds__(256) void cast_to_bf16(const void* __restrict__ in,
                                                    __bf16* __restrict__ out,
                                                    const int* __restrict__ flag, int n) {
  int isbf = flag[0];
  int i = blockIdx.x * 256 + threadIdx.x;
  if (i < n) out[i] = (__bf16)ldf(in, i, isbf);
}

// ---- transpose raw weight [R][C] (fp32/bf16 per flag) -> bf16 [C][R] ----
__global__ __launch_bounds__(256) void transpose_cast(const void* __restrict__ in,
                                                      __bf16* __restrict__ out,
                                                      const int* __restrict__ flag,
                                                      int R, int C) {
  __shared__ float tile[32][33];
  int isbf = flag[0];
  const int tx = threadIdx.x & 31, ty = threadIdx.x >> 5;
  const int r0 = blockIdx.y * 32, c0 = blockIdx.x * 32;
#pragma unroll
  for (int i = 0; i < 4; i++) {
    int r = ty + i * 8;
    tile[r][tx] = ldf(in, (size_t)(r0 + r) * C + c0 + tx, isbf);
  }
  __syncthreads();
#pragma unroll
  for (int i = 0; i < 4; i++) {
    int r = ty + i * 8;
    out[(size_t)(c0 + r) * R + r0 + tx] = (__bf16)tile[tx][r];
  }
}

// ---- internal bf16 transpose (for V): in[z][R][C] -> out[z][C][R] ----
__global__ __launch_bounds__(256) void transpose_v(const __bf16* __restrict__ in,
                                                   __bf16* __restrict__ out, int R, int C) {
  __shared__ __bf16 tile[32][33];
  const size_t bofs = (size_t)blockIdx.z * R * C;
  in += bofs; out += bofs;
  const int tx = threadIdx.x & 31, ty = threadIdx.x >> 5;
  const int r0 = blockIdx.y * 32, c0 = blockIdx.x * 32;
#pragma unroll
  for (int i = 0; i < 4; i++) {
    int r = ty + i * 8;
    tile[r][tx] = in[(size_t)(r0 + r) * C + c0 + tx];
  }
  __syncthreads();
#pragma unroll
  for (int i = 0; i < 4; i++) {
    int r = ty + i * 8;
    out[(size_t)(c0 + r) * R + r0 + tx] = tile[tx][r];
  }
}

// ---- bias buffer: float[4096] = [bq|bk|bv|bo] ----
__global__ void build_bias(const void* bq, const void* bk, const void* bv, const void* bo,
                           float* __restrict__ bias, const int* __restrict__ flag) {
  int isbf = flag[0];
  int i = blockIdx.x * 256 + threadIdx.x;
  if (i < 1024)      bias[i] = ldf(bq, i, isbf);
  else if (i < 2048) bias[i] = ldf(bk, i - 1024, isbf);
  else if (i < 3072) bias[i] = ldf(bv, i - 2048, isbf);
  else if (i < 4096) bias[i] = ldf(bo, i - 3072, isbf);
}

// ---------------- GEMM: C[M,N] = A[M,K] @ Bt[N,K]^T + bias ----------------
template <int DYN>
__global__ __launch_bounds__(256, 2) void gemm_bt(const __bf16* __restrict__ A,
                                                  const __bf16* __restrict__ Bt,
                                                  const float* __restrict__ bias,
                                                  void* __restrict__ Cout,
                                                  const int* __restrict__ flag,
                                                  int M, int N, int K) {
  __shared__ __align__(16) __bf16 As[128 * 64];
  __shared__ __align__(16) __bf16 Bs[128 * 64];
  const int tid = threadIdx.x;
  const int wid = tid >> 6, lane = tid & 63;
  const int m_blk = blockIdx.x * 128, n_blk = blockIdx.y * 128;
  const int wm = (wid & 1) * 64, wn = (wid >> 1) * 64;
  const int l8 = lane >> 3, l7 = lane & 7;
  const int cc = l7 ^ (l8 & 7);           // chunk this lane fetches when staging
  const int q4 = lane >> 4, l15 = lane & 15;

  f32x4 acc[4][4] = {};

  for (int kb = 0; kb < K; kb += 64) {
    __syncthreads();
#pragma unroll
    for (int i = 0; i < 4; i++) {
      int row = i * 32 + wid * 8 + l8;    // local row 0..127
      async_copy16(A + (size_t)(m_blk + row) * K + kb + cc * 8,
                   As + (i * 32 + wid * 8) * 64);
      async_copy16(Bt + (size_t)(n_blk + row) * K + kb + cc * 8,
                   Bs + (i * 32 + wid * 8) * 64);
    }
    __syncthreads();
#pragma unroll
    for (int k0 = 0; k0 < 64; k0 += 32) {
      bf16x8 a[4], b[4];
#pragma unroll
      for (int i = 0; i < 4; i++) {
        int ra = wm + i * 16 + l15;
        int ba = ra * 8 + (((k0 >> 3) + q4) ^ (ra & 7));
        a[i] = *(const bf16x8*)&As[ba * 8];
        int rb = wn + i * 16 + l15;
        int bb = rb * 8 + (((k0 >> 3) + q4) ^ (rb & 7));
        b[i] = *(const bf16x8*)&Bs[bb * 8];
      }
#pragma unroll
      for (int i = 0; i < 4; i++)
#pragma unroll
        for (int j = 0; j < 4; j++)
          acc[i][j] = __builtin_amdgcn_mfma_f32_16x16x32_bf16(a[i], b[j], acc[i][j], 0, 0, 0);
    }
  }

  const int isbf = DYN ? flag[0] : 1;
  float bcol[4];
#pragma unroll
  for (int j = 0; j < 4; j++) bcol[j] = bias[n_blk + wn + j * 16 + l15];
#pragma unroll
  for (int i = 0; i < 4; i++)
#pragma unroll
    for (int j = 0; j < 4; j++) {
      int col = n_blk + wn + j * 16 + l15;
#pragma unroll
      for (int r = 0; r < 4; r++) {
        int row = m_blk + wm + i * 16 + q4 * 4 + r;
        float v = acc[i][j][r] + bcol[j];
        size_t idx = (size_t)row * N + col;
        if (isbf) ((__bf16*)Cout)[idx] = (__bf16)v;
        else      ((float*)Cout)[idx] = v;
      }
    }
}

// ---------------- per-head LN + RoPE + cast; head channels via h*192 scramble ----------------
__global__ __launch_bounds__(256) void ln_rope(const __bf16* __restrict__ qkv,
                                               const void* __restrict__ rcos,
                                               const void* __restrict__ rsin,
                                               const void* __restrict__ qw,
                                               const void* __restrict__ qb,
                                               const void* __restrict__ kw,
                                               const void* __restrict__ kb_,
                                               const int* __restrict__ flag,
                                               __bf16* __restrict__ Qp,
                                               __bf16* __restrict__ Kp,
                                               __bf16* __restrict__ Vbf) {
  const int isbf = flag[0];
  const int unit = blockIdx.x * 4 + (threadIdx.x >> 6);
  const int lane = threadIdx.x & 63;
  const int h = unit & 15, n = (unit >> 4) & 2047, b = unit >> 15;
  const size_t tok = (size_t)b * 2048 + n;
  const __bf16* base = qkv + tok * 3072 + h * 192;
  float qv = (float)base[lane], kv = (float)base[64 + lane], vv = (float)base[128 + lane];

  float sq = qv, sk = kv;
#pragma unroll
  for (int m = 1; m < 64; m <<= 1) { sq += __shfl_xor(sq, m, 64); sk += __shfl_xor(sk, m, 64); }
  float muq = sq * (1.0f / 64.0f), muk = sk * (1.0f / 64.0f);
  float tq = qv - muq, tk = kv - muk;
  float vq = tq * tq, vk = tk * tk;
#pragma unroll
  for (int m = 1; m < 64; m <<= 1) { vq += __shfl_xor(vq, m, 64); vk += __shfl_xor(vk, m, 64); }
  float rsq = rsqrtf(vq * (1.0f / 64.0f) + 1e-6f);
  float rsk = rsqrtf(vk * (1.0f / 64.0f) + 1e-6f);
  float qn = tq * rsq * ldf(qw, lane, isbf) + ldf(qb, lane, isbf);
  float kn = tk * rsk * ldf(kw, lane, isbf) + ldf(kb_, lane, isbf);

  float c = ldf(rcos, tok * 64 + lane, isbf), s = ldf(rsin, tok * 64 + lane, isbf);
  float qpart = __shfl_xor(qn, 32, 64), kpart = __shfl_xor(kn, 32, 64);
  float qrh = (lane < 32) ? -qpart : qpart;
  float krh = (lane < 32) ? -kpart : kpart;
  float qr = qn * c + qrh * s;
  float kr = kn * c + krh * s;

  const size_t oidx = ((size_t)(b * 16 + h) * 2048 + n) * 64 + lane;
  Qp[oidx] = (__bf16)(qr * 0.1803368801111204f);  // 0.125 * log2(e)
  Kp[oidx] = (__bf16)kr;
  Vbf[oidx] = (__bf16)vv;
}

// ---------------- flash attention, transposed-S formulation ----------------
// grid (16 q-blocks, 32 bh), 4 waves x 32 q rows, KT=64 keys/iter, double-buffered K/V.
// One __syncthreads per iter: its vmcnt(0) drain targets loads issued a FULL iteration
// earlier (hidden), and it orders prior reads of buf^1 before this iter's prefetch
// writes into buf^1 (the round-3 race).
// S^T = K·Q^T -> per-lane softmax rows (2 shfls/reduction); P packed b64 to LDS;
// O^T = V^T·P accumulated in C-layout [d][q].
__global__ __launch_bounds__(256, 2) void attn(const __bf16* __restrict__ Qp,
                                               const __bf16* __restrict__ Kp,
                                               const __bf16* __restrict__ Vt,
                                               __bf16* __restrict__ Obuf) {
  __shared__ __align__(16) __bf16 sK[2][4096];   // [buf][(g=ks*2+c)*64 + lane]*8
  __shared__ __align__(16) __bf16 sV[2][4096];   // [buf][(g=ds*2+c)*64 + lane]*8
  __shared__ __align__(16) __bf16 sP[4][32 * 72];// per-wave: [q 0..31][key 0..63 +pad8]

  const int tid = threadIdx.x, wid = tid >> 6, lane = tid & 63;
  const int q4 = lane >> 4, l15 = lane & 15;
  const int bh = blockIdx.y;
  const int q0w = blockIdx.x * 128 + wid * 32;
  const __bf16* Qb = Qp + (size_t)bh * 2048 * 64;
  const __bf16* Kb = Kp + (size_t)bh * 2048 * 64;
  const __bf16* Vb = Vt + (size_t)bh * 64 * 2048;
  __bf16* sPw = &sP[wid][0];

  // Q fragments (B-operand): B[n=q=l15][k = q4*8 + j], 2 chains of 32 d
  bf16x8 qf[2][2];
#pragma unroll
  for (int qs = 0; qs < 2; qs++)
#pragma unroll
    for (int c = 0; c < 2; c++)
      qf[qs][c] = *(const bf16x8*)&Qb[(size_t)(q0w + qs * 16 + l15) * 64 + c * 32 + q4 * 8];

  f32x4 o[2][4] = {};
  float mst[2] = {-3.0e38f, -3.0e38f}, lst[2] = {0.f, 0.f};

  // stage tile at key offset kt into buffer bf (4 async copies per wave)
#define STAGE(kt, bf)                                                                   \
  do {                                                                                  \
    async_copy16(Kb + (size_t)((kt) + wid * 16 + l15) * 64 + q4 * 8,                    \
                 &sK[bf][(wid * 2 + 0) * 512]);                                         \
    async_copy16(Kb + (size_t)((kt) + wid * 16 + l15) * 64 + 32 + q4 * 8,               \
                 &sK[bf][(wid * 2 + 1) * 512]);                                         \
    async_copy16(Vb + (size_t)(wid * 16 + l15) * 2048 + (kt) + q4 * 8,                  \
                 &sV[bf][(wid * 2 + 0) * 512]);                                         \
    async_copy16(Vb + (size_t)(wid * 16 + l15) * 2048 + (kt) + 32 + q4 * 8,             \
                 &sV[bf][(wid * 2 + 1) * 512]);                                         \
  } while (0)

  STAGE(0, 0);

  for (int it = 0; it < 32; ++it) {
    const int buf = it & 1;
    // all waves done reading buf^1 (it-1 compute) AND all loads into buf landed
    __syncthreads();
    if (it < 31) STAGE((it + 1) * 64, buf ^ 1);

    // ---- QK^T (S^T): A = K rows (4 subs of 16 keys), B = Q (2 subs of 16 q) ----
    f32x4 sc[2][4];
#pragma unroll
    for (int ks = 0; ks < 4; ks++) {
      bf16x8 ak0 = *(const bf16x8*)&sK[buf][((ks * 2 + 0) * 64 + lane) * 8];
      bf16x8 ak1 = *(const bf16x8*)&sK[buf][((ks * 2 + 1) * 64 + lane) * 8];
#pragma unroll
      for (int qs = 0; qs < 2; qs++) {
        f32x4 z = {0.f, 0.f, 0.f, 0.f};
        z = __builtin_amdgcn_mfma_f32_16x16x32_bf16(ak0, qf[qs][0], z, 0, 0, 0);
        z = __builtin_amdgcn_mfma_f32_16x16x32_bf16(ak1, qf[qs][1], z, 0, 0, 0);
        sc[qs][ks] = z;
      }
    }

    // ---- online softmax: rows in-lane (keys = ks*16 + q4*4 + r), reduce over q4 ----
#pragma unroll
    for (int qs = 0; qs < 2; qs++) {
      float mx = sc[qs][0][0];
#pragma unroll
      for (int ks = 0; ks < 4; ks++)
#pragma unroll
        for (int r = 0; r < 4; r++) mx = fmaxf(mx, sc[qs][ks][r]);
      mx = fmaxf(mx, __shfl_xor(mx, 16, 64));
      mx = fmaxf(mx, __shfl_xor(mx, 32, 64));
      float mn = fmaxf(mst[qs], mx);
      float a = exp2f(mst[qs] - mn);
      mst[qs] = mn;
      float sum = 0.f;
#pragma unroll
      for (int ks = 0; ks < 4; ks++) {
        union { __bf16 h[4]; uint2 u; } pk;
#pragma unroll
        for (int r = 0; r < 4; r++) {
          float p = exp2f(sc[qs][ks][r] - mn);
          sum += p;
          pk.h[r] = (__bf16)p;
        }
        *(uint2*)&sPw[(qs * 16 + l15) * 72 + ks * 16 + q4 * 4] = pk.u;
      }
      sum += __shfl_xor(sum, 16, 64);
      sum += __shfl_xor(sum, 32, 64);
      lst[qs] = lst[qs] * a + sum;
#pragma unroll
      for (int ds = 0; ds < 4; ds++)
#pragma unroll
        for (int r = 0; r < 4; r++) o[qs][ds][r] *= a;
    }
    asm volatile("s_waitcnt lgkmcnt(0)" ::: "memory");  // P writes -> P reads (same wave)

    // ---- PV (O^T += V^T·P): A = V^T rows (4 subs of 16 d), B = P (2 q subs) ----
    bf16x8 pb[2][2];
#pragma unroll
    for (int qs = 0; qs < 2; qs++)
#pragma unroll
      for (int c = 0; c < 2; c++)
        pb[qs][c] = *(const bf16x8*)&sPw[(qs * 16 + l15) * 72 + c * 32 + q4 * 8];
#pragma unroll
    for (int ds = 0; ds < 4; ds++) {
      bf16x8 av0 = *(const bf16x8*)&sV[buf][((ds * 2 + 0) * 64 + lane) * 8];
      bf16x8 av1 = *(const bf16x8*)&sV[buf][((ds * 2 + 1) * 64 + lane) * 8];
#pragma unroll
      for (int qs = 0; qs < 2; qs++) {
        o[qs][ds] = __builtin_amdgcn_mfma_f32_16x16x32_bf16(av0, pb[qs][0], o[qs][ds], 0, 0, 0);
        o[qs][ds] = __builtin_amdgcn_mfma_f32_16x16x32_bf16(av1, pb[qs][1], o[qs][ds], 0, 0, 0);
      }
    }
  }
#undef STAGE

  // ---- epilogue: O^T C-layout [d = ds*16+q4*4+r][q = qs*16+l15] -> Obuf[b][q][h*64+d]
  const int b = bh >> 4, h = bh & 15;
#pragma unroll
  for (int qs = 0; qs < 2; qs++) {
    float rl = 1.0f / lst[qs];
    size_t base = (size_t)(b * 2048 + q0w + qs * 16 + l15) * 1024 + h * 64;
#pragma unroll
    for (int ds = 0; ds < 4; ds++) {
      union { __bf16 h4[4]; uint2 u; } pk;
#pragma unroll
      for (int r = 0; r < 4; r++) pk.h4[r] = (__bf16)(o[qs][ds][r] * rl);
      *(uint2*)&Obuf[base + ds * 16 + q4 * 4] = pk.u;
    }
  }
}

extern "C" void kernel_launch(void* const* d_in, const int* in_sizes, int n_in,
                              void* d_out, int out_size, void* d_ws, size_t ws_size,
                              hipStream_t stream) {
  const void* x   = d_in[0];
  const void* rc  = d_in[1];
  const void* rs  = d_in[2];
  const void* Wq  = d_in[3];
  const void* bq  = d_in[4];
  const void* Wk  = d_in[5];
  const void* bk  = d_in[6];
  const void* Wv  = d_in[7];
  const void* bv  = d_in[8];
  const void* qnw = d_in[9];
  const void* qnb = d_in[10];
  const void* knw = d_in[11];
  const void* knb = d_in[12];
  const void* Wo  = d_in[13];
  const void* bo  = d_in[14];

  char* ws = (char*)d_ws;
  __bf16* qkv  = (__bf16*)ws;                // [4096][3072] (24 MB); dies before Vt/Obuf live
  __bf16* Vt   = (__bf16*)ws;                // [32][64][2048] (8 MB)
  __bf16* Obuf = (__bf16*)(ws + 16777216);   // [4096][1024] (8 MB)
  __bf16* Qp   = (__bf16*)(ws + 25165824);   // [32][2048][64]
  __bf16* Kp   = (__bf16*)(ws + 33554432);
  __bf16* Vbf  = (__bf16*)(ws + 41943040);
  __bf16* Wt   = (__bf16*)(ws + 50331648);   // [3072][1024] = (Wq^T;Wk^T;Wv^T)
  __bf16* Wot  = (__bf16*)(ws + 56623104);   // [1024][1024]
  float*  bias = (float*)(ws + 58720256);    // [4096] = bq|bk|bv|bo
  __bf16* x_bf = (__bf16*)(ws + 58736640);   // [4096][1024]
  int*    flag = (int*)(ws + 67125248);

  detect_dtype<<<1, 64, 0, stream>>>((const unsigned short*)x, flag);
  cast_to_bf16<<<16384, 256, 0, stream>>>(x, x_bf, flag, 4096 * 1024);
  transpose_cast<<<dim3(32, 32), 256, 0, stream>>>(Wq, Wt, flag, 1024, 1024);
  transpose_cast<<<dim3(32, 32), 256, 0, stream>>>(Wk, Wt + 1024 * 1024, flag, 1024, 1024);
  transpose_cast<<<dim3(32, 32), 256, 0, stream>>>(Wv, Wt + 2 * 1024 * 1024, flag, 1024, 1024);
  transpose_cast<<<dim3(32, 32), 256, 0, stream>>>(Wo, Wot, flag, 1024, 1024);
  build_bias<<<16, 256, 0, stream>>>(bq, bk, bv, bo, bias, flag);

  gemm_bt<0><<<dim3(32, 24), 256, 0, stream>>>(x_bf, Wt, bias, qkv, flag, 4096, 3072, 1024);
  ln_rope<<<16384, 256, 0, stream>>>(qkv, rc, rs, qnw, qnb, knw, knb, flag, Qp, Kp, Vbf);
  transpose_v<<<dim3(2, 64, 32), 256, 0, stream>>>(Vbf, Vt, 2048, 64);
  attn<<<dim3(16, 32), 256, 0, stream>>>(Qp, Kp, Vt, Obuf);
  gemm_bt<1><<<dim3(32, 8), 256, 0, stream>>>(Obuf, Wot, bias + 3072, d_out, flag, 4096, 1024, 1024);
}

// Round 5
// 247.676 us; speedup vs baseline: 1.5748x; 1.0992x over previous
//
#include <hip/hip_runtime.h>

typedef __attribute__((ext_vector_type(8))) __bf16 bf16x8;
typedef __attribute__((ext_vector_type(4))) float  f32x4;

#define DEV __device__ __forceinline__

DEV void async_copy16(const void* g, void* l) {
  __builtin_amdgcn_global_load_lds((const __attribute__((address_space(1))) void*)g,
                                   (__attribute__((address_space(3))) void*)l, 16, 0, 0);
}

// load element i of a raw input as float; isbf chooses bf16 vs fp32 interpretation
DEV float ldf(const void* p, size_t i, int isbf) {
  if (isbf) {
    unsigned int w = ((unsigned int)((const unsigned short*)p)[i]) << 16;
    float f; __builtin_memcpy(&f, &w, 4); return f;
  }
  return ((const float*)p)[i];
}

// ---- dtype probe: flag=1 if inputs are bf16, 0 if fp32 ----
__global__ void detect_dtype(const unsigned short* __restrict__ x, int* __restrict__ flag) {
  int bad = 0;
#pragma unroll
  for (int i = 0; i < 4; i++) {
    unsigned short u = x[threadIdx.x + i * 64];
    int e = (u >> 7) & 0xFF;
    if (e >= 0x90) bad = 1;  // |v| >= 2^17 or Inf/NaN -> cannot be real bf16 data
  }
  int anybad = __any(bad);
  if (threadIdx.x == 0) flag[0] = anybad ? 0 : 1;
}

// ---- fused prep: z<4 -> transpose weight z into bf16 [C][R]; z==4 -> x copy + bias ----
__global__ __launch_bounds__(256) void prep(const void* __restrict__ Wq,
                                            const void* __restrict__ Wk,
                                            const void* __restrict__ Wv,
                                            const void* __restrict__ Wo,
                                            const void* __restrict__ x,
                                            const void* __restrict__ bq,
                                            const void* __restrict__ bk,
                                            const void* __restrict__ bv,
                                            const void* __restrict__ bo,
                                            const int* __restrict__ flag,
                                            __bf16* __restrict__ Wt,
                                            __bf16* __restrict__ Wot,
                                            __bf16* __restrict__ x_bf,
                                            float* __restrict__ bias) {
  __shared__ float tile[32][33];
  const int isbf = flag[0];
  const int tid = threadIdx.x;
  const int z = blockIdx.z;

  if (z < 4) {
    const void* in = (z == 0) ? Wq : (z == 1) ? Wk : (z == 2) ? Wv : Wo;
    __bf16* out = (z < 3) ? (Wt + (size_t)z * 1024 * 1024) : Wot;
    const int tx = tid & 31, ty = tid >> 5;
    const int r0 = blockIdx.y * 32, c0 = blockIdx.x * 32;
#pragma unroll
    for (int i = 0; i < 4; i++) {
      int r = ty + i * 8;
      tile[r][tx] = ldf(in, (size_t)(r0 + r) * 1024 + c0 + tx, isbf);
    }
    __syncthreads();
#pragma unroll
    for (int i = 0; i < 4; i++) {
      int r = ty + i * 8;
      out[(size_t)(c0 + r) * 1024 + r0 + tx] = (__bf16)tile[tx][r];
    }
  } else {
    const int id = blockIdx.y * 32 + blockIdx.x;  // 0..1023; 4096 x-elems per block
    if (isbf) {
#pragma unroll
      for (int j = 0; j < 4; j++) {
        int idx = id * 1024 + j * 256 + tid;      // uint2 = 4 bf16
        ((uint2*)x_bf)[idx] = ((const uint2*)x)[idx];
      }
    } else {
#pragma unroll
      for (int j = 0; j < 4; j++) {
        int idx = id * 1024 + j * 256 + tid;
        float4 f = ((const float4*)x)[idx];
        union { __bf16 h[4]; uint2 u; } pk;
        pk.h[0] = (__bf16)f.x; pk.h[1] = (__bf16)f.y;
        pk.h[2] = (__bf16)f.z; pk.h[3] = (__bf16)f.w;
        ((uint2*)x_bf)[idx] = pk.u;
      }
    }
    if (id < 16) {
      int i = id * 256 + tid;
      if (i < 1024)      bias[i] = ldf(bq, i, isbf);
      else if (i < 2048) bias[i] = ldf(bk, i - 1024, isbf);
      else if (i < 3072) bias[i] = ldf(bv, i - 2048, isbf);
      else               bias[i] = ldf(bo, i - 3072, isbf);
    }
  }
}

// ---------------- GEMM: C[M,N] = A[M,K] @ Bt[N,K]^T + bias ----------------
template <int DYN>
__global__ __launch_bounds__(256, 2) void gemm_bt(const __bf16* __restrict__ A,
                                                  const __bf16* __restrict__ Bt,
                                                  const float* __restrict__ bias,
                                                  void* __restrict__ Cout,
                                                  const int* __restrict__ flag,
                                                  int M, int N, int K) {
  __shared__ __align__(16) __bf16 As[128 * 64];
  __shared__ __align__(16) __bf16 Bs[128 * 64];
  const int tid = threadIdx.x;
  const int wid = tid >> 6, lane = tid & 63;
  const int m_blk = blockIdx.x * 128, n_blk = blockIdx.y * 128;
  const int wm = (wid & 1) * 64, wn = (wid >> 1) * 64;
  const int l8 = lane >> 3, l7 = lane & 7;
  const int cc = l7 ^ (l8 & 7);
  const int q4 = lane >> 4, l15 = lane & 15;

  f32x4 acc[4][4] = {};

  for (int kb = 0; kb < K; kb += 64) {
    __syncthreads();
#pragma unroll
    for (int i = 0; i < 4; i++) {
      int row = i * 32 + wid * 8 + l8;
      async_copy16(A + (size_t)(m_blk + row) * K + kb + cc * 8,
                   As + (i * 32 + wid * 8) * 64);
      async_copy16(Bt + (size_t)(n_blk + row) * K + kb + cc * 8,
                   Bs + (i * 32 + wid * 8) * 64);
    }
    __syncthreads();
#pragma unroll
    for (int k0 = 0; k0 < 64; k0 += 32) {
      bf16x8 a[4], b[4];
#pragma unroll
      for (int i = 0; i < 4; i++) {
        int ra = wm + i * 16 + l15;
        int ba = ra * 8 + (((k0 >> 3) + q4) ^ (ra & 7));
        a[i] = *(const bf16x8*)&As[ba * 8];
        int rb = wn + i * 16 + l15;
        int bb = rb * 8 + (((k0 >> 3) + q4) ^ (rb & 7));
        b[i] = *(const bf16x8*)&Bs[bb * 8];
      }
#pragma unroll
      for (int i = 0; i < 4; i++)
#pragma unroll
        for (int j = 0; j < 4; j++)
          acc[i][j] = __builtin_amdgcn_mfma_f32_16x16x32_bf16(a[i], b[j], acc[i][j], 0, 0, 0);
    }
  }

  const int isbf = DYN ? flag[0] : 1;
  float bcol[4];
#pragma unroll
  for (int j = 0; j < 4; j++) bcol[j] = bias[n_blk + wn + j * 16 + l15];
#pragma unroll
  for (int i = 0; i < 4; i++)
#pragma unroll
    for (int j = 0; j < 4; j++) {
      int col = n_blk + wn + j * 16 + l15;
#pragma unroll
      for (int r = 0; r < 4; r++) {
        int row = m_blk + wm + i * 16 + q4 * 4 + r;
        float v = acc[i][j][r] + bcol[j];
        size_t idx = (size_t)row * N + col;
        if (isbf) ((__bf16*)Cout)[idx] = (__bf16)v;
        else      ((float*)Cout)[idx] = v;
      }
    }
}

// ---------------- LN + RoPE + V-transpose (fused) ----------------
// grid (32 n-chunks, 32 bh). Each wave: 16 sequential tokens, lane = d.
// Q/K written row-contiguous; V gathered in LDS 64d x 64n tile, written transposed.
__global__ __launch_bounds__(256) void ln_rope_v(const __bf16* __restrict__ qkv,
                                                 const void* __restrict__ rcos,
                                                 const void* __restrict__ rsin,
                                                 const void* __restrict__ qw,
                                                 const void* __restrict__ qb,
                                                 const void* __restrict__ kw,
                                                 const void* __restrict__ kb_,
                                                 const int* __restrict__ flag,
                                                 __bf16* __restrict__ Qp,
                                                 __bf16* __restrict__ Kp,
                                                 __bf16* __restrict__ Vt) {
  __shared__ __bf16 vt[64][68];  // stride 68: 8B-aligned rows, 2-way (free) column writes
  const int isbf = flag[0];
  const int tid = threadIdx.x, w = tid >> 6, lane = tid & 63;
  const int bh = blockIdx.y, h = bh & 15, b = bh >> 4;
  const int n0 = blockIdx.x * 64;

  float gq = ldf(qw, lane, isbf), bq_ = ldf(qb, lane, isbf);
  float gk = ldf(kw, lane, isbf), bk_ = ldf(kb_, lane, isbf);

  for (int t = 0; t < 16; t++) {
    const int n = n0 + w * 16 + t;
    const size_t tok = (size_t)b * 2048 + n;
    const __bf16* base = qkv + tok * 3072 + h * 192;
    float qv = (float)base[lane], kv = (float)base[64 + lane], vv = (float)base[128 + lane];

    float sq = qv, sk = kv;
#pragma unroll
    for (int m = 1; m < 64; m <<= 1) { sq += __shfl_xor(sq, m, 64); sk += __shfl_xor(sk, m, 64); }
    float muq = sq * (1.0f / 64.0f), muk = sk * (1.0f / 64.0f);
    float tq = qv - muq, tk = kv - muk;
    float vq = tq * tq, vk = tk * tk;
#pragma unroll
    for (int m = 1; m < 64; m <<= 1) { vq += __shfl_xor(vq, m, 64); vk += __shfl_xor(vk, m, 64); }
    float rsq = rsqrtf(vq * (1.0f / 64.0f) + 1e-6f);
    float rsk = rsqrtf(vk * (1.0f / 64.0f) + 1e-6f);
    float qn = tq * rsq * gq + bq_;
    float kn = tk * rsk * gk + bk_;

    float c = ldf(rcos, tok * 64 + lane, isbf), s = ldf(rsin, tok * 64 + lane, isbf);
    float qpart = __shfl_xor(qn, 32, 64), kpart = __shfl_xor(kn, 32, 64);
    float qrh = (lane < 32) ? -qpart : qpart;
    float krh = (lane < 32) ? -kpart : kpart;

    const size_t oidx = ((size_t)bh * 2048 + n) * 64 + lane;
    Qp[oidx] = (__bf16)((qn * c + qrh * s) * 0.1803368801111204f);  // 0.125 * log2(e)
    Kp[oidx] = (__bf16)(kn * c + krh * s);
    vt[lane][w * 16 + t] = (__bf16)vv;
  }
  __syncthreads();
  // write out Vt[bh][d][n]: thread -> row d=tid>>2, cols (tid&3)*16 .. +15
  const int row = tid >> 2, qt = tid & 3;
  size_t gbase = (size_t)bh * 64 * 2048 + (size_t)row * 2048 + n0 + qt * 16;
#pragma unroll
  for (int u = 0; u < 4; u++)
    *(uint2*)&Vt[gbase + u * 4] = *(const uint2*)&vt[row][qt * 16 + u * 4];
}

// ---------------- flash attention, transposed-S, no-max softmax ----------------
// Scores bounded (post-LN, |s*0.18| small) -> p = exp2(s) directly: no running max,
// no per-iter O rescale, l-reduction deferred to epilogue. P stored in consumer
// fragment order -> linear conflict-free b128 reads.
__global__ __launch_bounds__(256, 2) void attn(const __bf16* __restrict__ Qp,
                                               const __bf16* __restrict__ Kp,
                                               const __bf16* __restrict__ Vt,
                                               __bf16* __restrict__ Obuf) {
  __shared__ __align__(16) __bf16 sK[2][4096];   // [buf][(g)*64 + lane]*8, frag order
  __shared__ __align__(16) __bf16 sV[2][4096];
  __shared__ __align__(16) __bf16 sP[4][2048];   // per-wave, B-frag order

  const int tid = threadIdx.x, wid = tid >> 6, lane = tid & 63;
  const int q4 = lane >> 4, l15 = lane & 15;
  const int bh = blockIdx.y;
  const int q0w = blockIdx.x * 128 + wid * 32;
  const __bf16* Qb = Qp + (size_t)bh * 2048 * 64;
  const __bf16* Kb = Kp + (size_t)bh * 2048 * 64;
  const __bf16* Vb = Vt + (size_t)bh * 64 * 2048;
  __bf16* sPw = &sP[wid][0];
  // producer-side sP offset base: ((q4>>1)*16 + l15)*8 + (q4&1)*4
  const int pbase = (q4 >> 1) * 128 + l15 * 8 + (q4 & 1) * 4;

  bf16x8 qf[2][2];
#pragma unroll
  for (int qs = 0; qs < 2; qs++)
#pragma unroll
    for (int c = 0; c < 2; c++)
      qf[qs][c] = *(const bf16x8*)&Qb[(size_t)(q0w + qs * 16 + l15) * 64 + c * 32 + q4 * 8];

  f32x4 o[2][4] = {};
  float lsum[2] = {0.f, 0.f};

#define STAGE(kt, bf)                                                                   \
  do {                                                                                  \
    async_copy16(Kb + (size_t)((kt) + wid * 16 + l15) * 64 + q4 * 8,                    \
                 &sK[bf][(wid * 2 + 0) * 512]);                                         \
    async_copy16(Kb + (size_t)((kt) + wid * 16 + l15) * 64 + 32 + q4 * 8,               \
                 &sK[bf][(wid * 2 + 1) * 512]);                                         \
    async_copy16(Vb + (size_t)(wid * 16 + l15) * 2048 + (kt) + q4 * 8,                  \
                 &sV[bf][(wid * 2 + 0) * 512]);                                         \
    async_copy16(Vb + (size_t)(wid * 16 + l15) * 2048 + (kt) + 32 + q4 * 8,             \
                 &sV[bf][(wid * 2 + 1) * 512]);                                         \
  } while (0)

  STAGE(0, 0);

  for (int it = 0; it < 32; ++it) {
    const int buf = it & 1;
    __syncthreads();  // readers of buf^1 done + loads into buf landed (issued last iter)
    if (it < 31) STAGE((it + 1) * 64, buf ^ 1);

    // ---- QK^T (S^T): A = K rows, B = Q ----
    f32x4 sc[2][4];
#pragma unroll
    for (int ks = 0; ks < 4; ks++) {
      bf16x8 ak0 = *(const bf16x8*)&sK[buf][((ks * 2 + 0) * 64 + lane) * 8];
      bf16x8 ak1 = *(const bf16x8*)&sK[buf][((ks * 2 + 1) * 64 + lane) * 8];
#pragma unroll
      for (int qs = 0; qs < 2; qs++) {
        f32x4 z = {0.f, 0.f, 0.f, 0.f};
        z = __builtin_amdgcn_mfma_f32_16x16x32_bf16(ak0, qf[qs][0], z, 0, 0, 0);
        z = __builtin_amdgcn_mfma_f32_16x16x32_bf16(ak1, qf[qs][1], z, 0, 0, 0);
        sc[qs][ks] = z;
      }
    }

    // ---- no-max softmax: p = exp2(s); store P in B-frag order; defer l reduce ----
#pragma unroll
    for (int qs = 0; qs < 2; qs++)
#pragma unroll
      for (int ks = 0; ks < 4; ks++) {
        union { __bf16 h[4]; uint2 u; } pk;
#pragma unroll
        for (int r = 0; r < 4; r++) {
          float p = exp2f(sc[qs][ks][r]);
          lsum[qs] += p;
          pk.h[r] = (__bf16)p;
        }
        *(uint2*)&sPw[(qs * 2 + (ks >> 1)) * 512 + (ks & 1) * 256 + pbase] = pk.u;
      }
    asm volatile("s_waitcnt lgkmcnt(0)" ::: "memory");  // P writes -> reads (same wave)

    // ---- PV (O^T += V^T·P) ----
    bf16x8 pb[2][2];
#pragma unroll
    for (int qs = 0; qs < 2; qs++)
#pragma unroll
      for (int c = 0; c < 2; c++)
        pb[qs][c] = *(const bf16x8*)&sPw[((qs * 2 + c) * 64 + lane) * 8];
#pragma unroll
    for (int ds = 0; ds < 4; ds++) {
      bf16x8 av0 = *(const bf16x8*)&sV[buf][((ds * 2 + 0) * 64 + lane) * 8];
      bf16x8 av1 = *(const bf16x8*)&sV[buf][((ds * 2 + 1) * 64 + lane) * 8];
#pragma unroll
      for (int qs = 0; qs < 2; qs++) {
        o[qs][ds] = __builtin_amdgcn_mfma_f32_16x16x32_bf16(av0, pb[qs][0], o[qs][ds], 0, 0, 0);
        o[qs][ds] = __builtin_amdgcn_mfma_f32_16x16x32_bf16(av1, pb[qs][1], o[qs][ds], 0, 0, 0);
      }
    }
  }
#undef STAGE

  // ---- epilogue: reduce l across q4 lanes; O^T [d][q] -> Obuf[b][q][h*64+d] ----
  const int b = bh >> 4, h = bh & 15;
#pragma unroll
  for (int qs = 0; qs < 2; qs++) {
    float l = lsum[qs];
    l += __shfl_xor(l, 16, 64);
    l += __shfl_xor(l, 32, 64);
    float rl = 1.0f / l;
    size_t base = (size_t)(b * 2048 + q0w + qs * 16 + l15) * 1024 + h * 64;
#pragma unroll
    for (int ds = 0; ds < 4; ds++) {
      union { __bf16 h4[4]; uint2 u; } pk;
#pragma unroll
      for (int r = 0; r < 4; r++) pk.h4[r] = (__bf16)(o[qs][ds][r] * rl);
      *(uint2*)&Obuf[base + ds * 16 + q4 * 4] = pk.u;
    }
  }
}

extern "C" void kernel_launch(void* const* d_in, const int* in_sizes, int n_in,
                              void* d_out, int out_size, void* d_ws, size_t ws_size,
                              hipStream_t stream) {
  const void* x   = d_in[0];
  const void* rc  = d_in[1];
  const void* rs  = d_in[2];
  const void* Wq  = d_in[3];
  const void* bq  = d_in[4];
  const void* Wk  = d_in[5];
  const void* bk  = d_in[6];
  const void* Wv  = d_in[7];
  const void* bv  = d_in[8];
  const void* qnw = d_in[9];
  const void* qnb = d_in[10];
  const void* knw = d_in[11];
  const void* knb = d_in[12];
  const void* Wo  = d_in[13];
  const void* bo  = d_in[14];

  char* ws = (char*)d_ws;
  __bf16* qkv  = (__bf16*)ws;                // [4096][3072] 24 MB; dead after ln_rope_v
  __bf16* Obuf = (__bf16*)ws;                // [4096][1024] 8 MB (aliases dead qkv)
  __bf16* Qp   = (__bf16*)(ws + 25165824);   // [32][2048][64] 8 MB
  __bf16* Kp   = (__bf16*)(ws + 33554432);   // 8 MB
  __bf16* Vt   = (__bf16*)(ws + 41943040);   // [32][64][2048] 8 MB
  __bf16* Wt   = (__bf16*)(ws + 50331648);   // [3072][1024] 6 MB
  __bf16* Wot  = (__bf16*)(ws + 56623104);   // [1024][1024] 2 MB
  float*  bias = (float*)(ws + 58720256);    // [4096]
  __bf16* x_bf = (__bf16*)(ws + 58736640);   // [4096][1024] 8 MB
  int*    flag = (int*)(ws + 67125248);

  detect_dtype<<<1, 64, 0, stream>>>((const unsigned short*)x, flag);
  prep<<<dim3(32, 32, 5), 256, 0, stream>>>(Wq, Wk, Wv, Wo, x, bq, bk, bv, bo, flag,
                                            Wt, Wot, x_bf, bias);
  gemm_bt<0><<<dim3(32, 24), 256, 0, stream>>>(x_bf, Wt, bias, qkv, flag, 4096, 3072, 1024);
  ln_rope_v<<<dim3(32, 32), 256, 0, stream>>>(qkv, rc, rs, qnw, qnb, knw, knb, flag,
                                              Qp, Kp, Vt);
  attn<<<dim3(16, 32), 256, 0, stream>>>(Qp, Kp, Vt, Obuf);
  gemm_bt<1><<<dim3(32, 8), 256, 0, stream>>>(Obuf, Wot, bias + 3072, d_out, flag,
                                              4096, 1024, 1024);
}

// Round 6
// 247.078 us; speedup vs baseline: 1.5786x; 1.0024x over previous
//
#include <hip/hip_runtime.h>

typedef __attribute__((ext_vector_type(8))) __bf16 bf16x8;
typedef __attribute__((ext_vector_type(4))) float  f32x4;

#define DEV __device__ __forceinline__

DEV void async_copy16(const void* g, void* l) {
  __builtin_amdgcn_global_load_lds((const __attribute__((address_space(1))) void*)g,
                                   (__attribute__((address_space(3))) void*)l, 16, 0, 0);
}

// load element i of a raw input as float; isbf chooses bf16 vs fp32 interpretation
DEV float ldf(const void* p, size_t i, int isbf) {
  if (isbf) {
    unsigned int w = ((unsigned int)((const unsigned short*)p)[i]) << 16;
    float f; __builtin_memcpy(&f, &w, 4); return f;
  }
  return ((const float*)p)[i];
}

// uniform per-block dtype probe on x's first 64 halfwords (scalar loads; all lanes agree)
// real-bf16 data has all exponents < 2^17; fp32-as-bf16 low halves are random-exponent.
DEV int detect_isbf(const unsigned short* __restrict__ x) {
  int bad = 0;
#pragma unroll
  for (int i = 0; i < 64; i++) {
    int e = (x[i] >> 7) & 0xFF;
    bad |= (e >= 0x90) ? 1 : 0;
  }
  return !bad;
}

// ---- fused prep: z<4 -> transpose weight z into bf16 [C][R]; z==4 -> x cast (fp32 only) + bias ----
__global__ __launch_bounds__(256) void prep(const void* __restrict__ Wq,
                                            const void* __restrict__ Wk,
                                            const void* __restrict__ Wv,
                                            const void* __restrict__ Wo,
                                            const void* __restrict__ x,
                                            const void* __restrict__ bq,
                                            const void* __restrict__ bk,
                                            const void* __restrict__ bv,
                                            const void* __restrict__ bo,
                                            __bf16* __restrict__ Wt,
                                            __bf16* __restrict__ Wot,
                                            __bf16* __restrict__ x_bf,
                                            float* __restrict__ bias) {
  __shared__ float tile[32][33];
  const int isbf = detect_isbf((const unsigned short*)x);
  const int tid = threadIdx.x;
  const int z = blockIdx.z;

  if (z < 4) {
    const void* in = (z == 0) ? Wq : (z == 1) ? Wk : (z == 2) ? Wv : Wo;
    __bf16* out = (z < 3) ? (Wt + (size_t)z * 1024 * 1024) : Wot;
    const int tx = tid & 31, ty = tid >> 5;
    const int r0 = blockIdx.y * 32, c0 = blockIdx.x * 32;
#pragma unroll
    for (int i = 0; i < 4; i++) {
      int r = ty + i * 8;
      tile[r][tx] = ldf(in, (size_t)(r0 + r) * 1024 + c0 + tx, isbf);
    }
    __syncthreads();
#pragma unroll
    for (int i = 0; i < 4; i++) {
      int r = ty + i * 8;
      out[(size_t)(c0 + r) * 1024 + r0 + tx] = (__bf16)tile[tx][r];
    }
  } else {
    const int id = blockIdx.y * 32 + blockIdx.x;  // 0..1023
    if (!isbf) {
#pragma unroll
      for (int j = 0; j < 4; j++) {
        int idx = id * 1024 + j * 256 + tid;
        float4 f = ((const float4*)x)[idx];
        union { __bf16 h[4]; uint2 u; } pk;
        pk.h[0] = (__bf16)f.x; pk.h[1] = (__bf16)f.y;
        pk.h[2] = (__bf16)f.z; pk.h[3] = (__bf16)f.w;
        ((uint2*)x_bf)[idx] = pk.u;
      }
    }
    if (id < 16) {
      int i = id * 256 + tid;
      if (i < 1024)      bias[i] = ldf(bq, i, isbf);
      else if (i < 2048) bias[i] = ldf(bk, i - 1024, isbf);
      else if (i < 3072) bias[i] = ldf(bv, i - 2048, isbf);
      else               bias[i] = ldf(bo, i - 3072, isbf);
    }
  }
}

// ---------------- GEMM: C[M,NT-tiled] = A[M,K] @ Bt[N,K]^T + bias ----------------
// DYN: output dtype per detected flag (else bf16). NT: n-tile (128 or 64). ALT: if
// input is bf16, read A from Aalt (the raw input) instead of the converted copy.
template <int DYN, int NT, int ALT>
__global__ __launch_bounds__(256, 2) void gemm_bt(const __bf16* __restrict__ A,
                                                  const __bf16* __restrict__ Aalt,
                                                  const __bf16* __restrict__ Bt,
                                                  const float* __restrict__ bias,
                                                  void* __restrict__ Cout,
                                                  const unsigned short* __restrict__ xdet,
                                                  int M, int N, int K) {
  constexpr int WN = NT / 2;     // wave n-extent
  constexpr int JB = WN / 16;    // b-frags per wave
  constexpr int NR = NT / 32;    // staging row-groups for Bs
  __shared__ __align__(16) __bf16 As[128 * 64];
  __shared__ __align__(16) __bf16 Bs[NT * 64];
  const int tid = threadIdx.x;
  const int wid = tid >> 6, lane = tid & 63;
  const int m_blk = blockIdx.x * 128, n_blk = blockIdx.y * NT;
  const int wm = (wid & 1) * 64, wn = (wid >> 1) * WN;
  const int l8 = lane >> 3, l7 = lane & 7;
  const int cc = l7 ^ (l8 & 7);
  const int q4 = lane >> 4, l15 = lane & 15;

  int isbf = 1;
  if (DYN || ALT) isbf = detect_isbf(xdet);
  const __bf16* Ap = (ALT && isbf) ? Aalt : A;

  f32x4 acc[4][JB] = {};

  for (int kb = 0; kb < K; kb += 64) {
    __syncthreads();
#pragma unroll
    for (int i = 0; i < 4; i++) {
      int row = i * 32 + wid * 8 + l8;
      async_copy16(Ap + (size_t)(m_blk + row) * K + kb + cc * 8,
                   As + (i * 32 + wid * 8) * 64);
    }
#pragma unroll
    for (int i = 0; i < NR; i++) {
      int row = i * 32 + wid * 8 + l8;
      async_copy16(Bt + (size_t)(n_blk + row) * K + kb + cc * 8,
                   Bs + (i * 32 + wid * 8) * 64);
    }
    __syncthreads();
#pragma unroll
    for (int k0 = 0; k0 < 64; k0 += 32) {
      bf16x8 a[4], b[JB];
#pragma unroll
      for (int i = 0; i < 4; i++) {
        int ra = wm + i * 16 + l15;
        int ba = ra * 8 + (((k0 >> 3) + q4) ^ (ra & 7));
        a[i] = *(const bf16x8*)&As[ba * 8];
      }
#pragma unroll
      for (int j = 0; j < JB; j++) {
        int rb = wn + j * 16 + l15;
        int bb = rb * 8 + (((k0 >> 3) + q4) ^ (rb & 7));
        b[j] = *(const bf16x8*)&Bs[bb * 8];
      }
#pragma unroll
      for (int i = 0; i < 4; i++)
#pragma unroll
        for (int j = 0; j < JB; j++)
          acc[i][j] = __builtin_amdgcn_mfma_f32_16x16x32_bf16(a[i], b[j], acc[i][j], 0, 0, 0);
    }
  }

  float bcol[JB];
#pragma unroll
  for (int j = 0; j < JB; j++) bcol[j] = bias[n_blk + wn + j * 16 + l15];
#pragma unroll
  for (int i = 0; i < 4; i++)
#pragma unroll
    for (int j = 0; j < JB; j++) {
      int col = n_blk + wn + j * 16 + l15;
#pragma unroll
      for (int r = 0; r < 4; r++) {
        int row = m_blk + wm + i * 16 + q4 * 4 + r;
        float v = acc[i][j][r] + bcol[j];
        size_t idx = (size_t)row * N + col;
        if (DYN && !isbf) ((float*)Cout)[idx] = v;
        else              ((__bf16*)Cout)[idx] = (__bf16)v;
      }
    }
}

// ---------------- LN + RoPE + V-transpose (fused) ----------------
__global__ __launch_bounds__(256) void ln_rope_v(const __bf16* __restrict__ qkv,
                                                 const void* __restrict__ rcos,
                                                 const void* __restrict__ rsin,
                                                 const void* __restrict__ qw,
                                                 const void* __restrict__ qb,
                                                 const void* __restrict__ kw,
                                                 const void* __restrict__ kb_,
                                                 const unsigned short* __restrict__ xdet,
                                                 __bf16* __restrict__ Qp,
                                                 __bf16* __restrict__ Kp,
                                                 __bf16* __restrict__ Vt) {
  __shared__ __bf16 vt[64][68];
  const int isbf = detect_isbf(xdet);
  const int tid = threadIdx.x, w = tid >> 6, lane = tid & 63;
  const int bh = blockIdx.y, h = bh & 15, b = bh >> 4;
  const int n0 = blockIdx.x * 64;

  float gq = ldf(qw, lane, isbf), bq_ = ldf(qb, lane, isbf);
  float gk = ldf(kw, lane, isbf), bk_ = ldf(kb_, lane, isbf);

  for (int t = 0; t < 16; t++) {
    const int n = n0 + w * 16 + t;
    const size_t tok = (size_t)b * 2048 + n;
    const __bf16* base = qkv + tok * 3072 + h * 192;
    float qv = (float)base[lane], kv = (float)base[64 + lane], vv = (float)base[128 + lane];

    float sq = qv, sk = kv;
#pragma unroll
    for (int m = 1; m < 64; m <<= 1) { sq += __shfl_xor(sq, m, 64); sk += __shfl_xor(sk, m, 64); }
    float muq = sq * (1.0f / 64.0f), muk = sk * (1.0f / 64.0f);
    float tq = qv - muq, tk = kv - muk;
    float vq = tq * tq, vk = tk * tk;
#pragma unroll
    for (int m = 1; m < 64; m <<= 1) { vq += __shfl_xor(vq, m, 64); vk += __shfl_xor(vk, m, 64); }
    float rsq = rsqrtf(vq * (1.0f / 64.0f) + 1e-6f);
    float rsk = rsqrtf(vk * (1.0f / 64.0f) + 1e-6f);
    float qn = tq * rsq * gq + bq_;
    float kn = tk * rsk * gk + bk_;

    float c = ldf(rcos, tok * 64 + lane, isbf), s = ldf(rsin, tok * 64 + lane, isbf);
    float qpart = __shfl_xor(qn, 32, 64), kpart = __shfl_xor(kn, 32, 64);
    float qrh = (lane < 32) ? -qpart : qpart;
    float krh = (lane < 32) ? -kpart : kpart;

    const size_t oidx = ((size_t)bh * 2048 + n) * 64 + lane;
    Qp[oidx] = (__bf16)((qn * c + qrh * s) * 0.1803368801111204f);  // 0.125 * log2(e)
    Kp[oidx] = (__bf16)(kn * c + krh * s);
    vt[lane][w * 16 + t] = (__bf16)vv;
  }
  __syncthreads();
  const int row = tid >> 2, qt = tid & 3;
  size_t gbase = (size_t)bh * 64 * 2048 + (size_t)row * 2048 + n0 + qt * 16;
#pragma unroll
  for (int u = 0; u < 4; u++)
    *(uint2*)&Vt[gbase + u * 4] = *(const uint2*)&vt[row][qt * 16 + u * 4];
}

// ---------------- flash attention: transposed-S, no-max softmax, 3-buffer pipeline ----------------
// Prefetch distance 2, waits are s_waitcnt vmcnt(4) (never 0 until the tail) + bare
// s_barrier: the prefetch stays in flight across the barrier (AITER-style). Q frags
// staged via global_load_lds too, so the loop has NO register-defining VMEM -> the
// compiler inserts no vmcnt waits of its own.
__global__ __launch_bounds__(256, 2) void attn(const __bf16* __restrict__ Qp,
                                               const __bf16* __restrict__ Kp,
                                               const __bf16* __restrict__ Vt,
                                               __bf16* __restrict__ Obuf) {
  __shared__ __align__(16) __bf16 sK[3][4096];   // [buf][(g)*64 + lane]*8, frag order
  __shared__ __align__(16) __bf16 sV[3][4096];
  __shared__ __align__(16) __bf16 sP[4][2048];   // per-wave; pre-loop: Q staging

  const int tid = threadIdx.x, wid = tid >> 6, lane = tid & 63;
  const int q4 = lane >> 4, l15 = lane & 15;
  const int bh = blockIdx.y;
  const int q0w = blockIdx.x * 128 + wid * 32;
  const __bf16* Qb = Qp + (size_t)bh * 2048 * 64;
  const __bf16* Kb = Kp + (size_t)bh * 2048 * 64;
  const __bf16* Vb = Vt + (size_t)bh * 64 * 2048;
  __bf16* sPw = &sP[wid][0];
  const int pbase = (q4 >> 1) * 128 + l15 * 8 + (q4 & 1) * 4;

#define STAGE(kt, bf)                                                                   \
  do {                                                                                  \
    async_copy16(Kb + (size_t)((kt) + wid * 16 + l15) * 64 + q4 * 8,                    \
                 &sK[bf][(wid * 2 + 0) * 512]);                                         \
    async_copy16(Kb + (size_t)((kt) + wid * 16 + l15) * 64 + 32 + q4 * 8,               \
                 &sK[bf][(wid * 2 + 1) * 512]);                                         \
    async_copy16(Vb + (size_t)(wid * 16 + l15) * 2048 + (kt) + q4 * 8,                  \
                 &sV[bf][(wid * 2 + 0) * 512]);                                         \
    async_copy16(Vb + (size_t)(wid * 16 + l15) * 2048 + (kt) + 32 + q4 * 8,             \
                 &sV[bf][(wid * 2 + 1) * 512]);                                         \
  } while (0)

  // stage Q tile (frag order) into this wave's sP region (4 copies, oldest in queue)
#pragma unroll
  for (int qs = 0; qs < 2; qs++)
#pragma unroll
    for (int c = 0; c < 2; c++)
      async_copy16(Qb + (size_t)(q0w + qs * 16 + l15) * 64 + c * 32 + q4 * 8,
                   &sPw[(qs * 2 + c) * 512]);
  STAGE(0, 0);
  STAGE(64, 1);
  asm volatile("s_waitcnt vmcnt(8)" ::: "memory");  // Q's 4 copies (oldest) landed

  bf16x8 qf[2][2];
#pragma unroll
  for (int qs = 0; qs < 2; qs++)
#pragma unroll
    for (int c = 0; c < 2; c++)
      qf[qs][c] = *(const bf16x8*)&sPw[((qs * 2 + c) * 64 + lane) * 8];

  f32x4 o[2][4] = {};
  float lsum[2] = {0.f, 0.f};
  int buf = 0;

  for (int it = 0; it < 32; ++it) {
    // tile it's copies were issued 2 iters ago; newest 4 in flight = tile it+1
    if (it < 31) asm volatile("s_waitcnt vmcnt(4)" ::: "memory");
    else         asm volatile("s_waitcnt vmcnt(0)" ::: "memory");
    asm volatile("s_barrier" ::: "memory");  // no lgkm/vm drain: prefetch stays in flight
    if (it <= 29) {
      int b2 = buf + 2; if (b2 >= 3) b2 -= 3;
      STAGE((it + 2) * 64, b2);
    }

    // ---- QK^T (S^T): A = K rows, B = Q ----
    f32x4 sc[2][4];
#pragma unroll
    for (int ks = 0; ks < 4; ks++) {
      bf16x8 ak0 = *(const bf16x8*)&sK[buf][((ks * 2 + 0) * 64 + lane) * 8];
      bf16x8 ak1 = *(const bf16x8*)&sK[buf][((ks * 2 + 1) * 64 + lane) * 8];
#pragma unroll
      for (int qs = 0; qs < 2; qs++) {
        f32x4 z = {0.f, 0.f, 0.f, 0.f};
        z = __builtin_amdgcn_mfma_f32_16x16x32_bf16(ak0, qf[qs][0], z, 0, 0, 0);
        z = __builtin_amdgcn_mfma_f32_16x16x32_bf16(ak1, qf[qs][1], z, 0, 0, 0);
        sc[qs][ks] = z;
      }
    }

    // ---- no-max softmax: p = exp2(s); store P in B-frag order; defer l reduce ----
#pragma unroll
    for (int qs = 0; qs < 2; qs++)
#pragma unroll
      for (int ks = 0; ks < 4; ks++) {
        union { __bf16 h[4]; uint2 u; } pk;
#pragma unroll
        for (int r = 0; r < 4; r++) {
          float p = exp2f(sc[qs][ks][r]);
          lsum[qs] += p;
          pk.h[r] = (__bf16)p;
        }
        *(uint2*)&sPw[(qs * 2 + (ks >> 1)) * 512 + (ks & 1) * 256 + pbase] = pk.u;
      }
    asm volatile("s_waitcnt lgkmcnt(0)" ::: "memory");  // P writes -> reads (same wave)

    // ---- PV (O^T += V^T·P) ----
    bf16x8 pb[2][2];
#pragma unroll
    for (int qs = 0; qs < 2; qs++)
#pragma unroll
      for (int c = 0; c < 2; c++)
        pb[qs][c] = *(const bf16x8*)&sPw[((qs * 2 + c) * 64 + lane) * 8];
#pragma unroll
    for (int ds = 0; ds < 4; ds++) {
      bf16x8 av0 = *(const bf16x8*)&sV[buf][((ds * 2 + 0) * 64 + lane) * 8];
      bf16x8 av1 = *(const bf16x8*)&sV[buf][((ds * 2 + 1) * 64 + lane) * 8];
#pragma unroll
      for (int qs = 0; qs < 2; qs++) {
        o[qs][ds] = __builtin_amdgcn_mfma_f32_16x16x32_bf16(av0, pb[qs][0], o[qs][ds], 0, 0, 0);
        o[qs][ds] = __builtin_amdgcn_mfma_f32_16x16x32_bf16(av1, pb[qs][1], o[qs][ds], 0, 0, 0);
      }
    }
    buf = (buf == 2) ? 0 : buf + 1;
  }
#undef STAGE

  // ---- epilogue: reduce l across q4 lanes; O^T [d][q] -> Obuf[b][q][h*64+d] ----
  const int b = bh >> 4, h = bh & 15;
#pragma unroll
  for (int qs = 0; qs < 2; qs++) {
    float l = lsum[qs];
    l += __shfl_xor(l, 16, 64);
    l += __shfl_xor(l, 32, 64);
    float rl = 1.0f / l;
    size_t base = (size_t)(b * 2048 + q0w + qs * 16 + l15) * 1024 + h * 64;
#pragma unroll
    for (int ds = 0; ds < 4; ds++) {
      union { __bf16 h4[4]; uint2 u; } pk;
#pragma unroll
      for (int r = 0; r < 4; r++) pk.h4[r] = (__bf16)(o[qs][ds][r] * rl);
      *(uint2*)&Obuf[base + ds * 16 + q4 * 4] = pk.u;
    }
  }
}

extern "C" void kernel_launch(void* const* d_in, const int* in_sizes, int n_in,
                              void* d_out, int out_size, void* d_ws, size_t ws_size,
                              hipStream_t stream) {
  const void* x   = d_in[0];
  const void* rc  = d_in[1];
  const void* rs  = d_in[2];
  const void* Wq  = d_in[3];
  const void* bq  = d_in[4];
  const void* Wk  = d_in[5];
  const void* bk  = d_in[6];
  const void* Wv  = d_in[7];
  const void* bv  = d_in[8];
  const void* qnw = d_in[9];
  const void* qnb = d_in[10];
  const void* knw = d_in[11];
  const void* knb = d_in[12];
  const void* Wo  = d_in[13];
  const void* bo  = d_in[14];
  const unsigned short* xdet = (const unsigned short*)x;

  char* ws = (char*)d_ws;
  __bf16* qkv  = (__bf16*)ws;                // [4096][3072] 24 MB; dead after ln_rope_v
  __bf16* Obuf = (__bf16*)ws;                // [4096][1024] 8 MB (aliases dead qkv)
  __bf16* Qp   = (__bf16*)(ws + 25165824);   // [32][2048][64] 8 MB
  __bf16* Kp   = (__bf16*)(ws + 33554432);   // 8 MB
  __bf16* Vt   = (__bf16*)(ws + 41943040);   // [32][64][2048] 8 MB
  __bf16* Wt   = (__bf16*)(ws + 50331648);   // [3072][1024] 6 MB
  __bf16* Wot  = (__bf16*)(ws + 56623104);   // [1024][1024] 2 MB
  float*  bias = (float*)(ws + 58720256);    // [4096]
  __bf16* x_bf = (__bf16*)(ws + 58736640);   // [4096][1024] 8 MB (fp32 path only)

  prep<<<dim3(32, 32, 5), 256, 0, stream>>>(Wq, Wk, Wv, Wo, x, bq, bk, bv, bo,
                                            Wt, Wot, x_bf, bias);
  gemm_bt<0, 128, 1><<<dim3(32, 24), 256, 0, stream>>>(x_bf, (const __bf16*)x, Wt, bias,
                                                       qkv, xdet, 4096, 3072, 1024);
  ln_rope_v<<<dim3(32, 32), 256, 0, stream>>>(qkv, rc, rs, qnw, qnb, knw, knb, xdet,
                                              Qp, Kp, Vt);
  attn<<<dim3(16, 32), 256, 0, stream>>>(Qp, Kp, Vt, Obuf);
  gemm_bt<1, 64, 0><<<dim3(32, 16), 256, 0, stream>>>(Obuf, nullptr, Wot, bias + 3072,
                                                      d_out, xdet, 4096, 1024, 1024);
}